// Round 2
// baseline (683.547 us; speedup 1.0000x reference)
//
#include <hip/hip_runtime.h>
#include <hip/hip_bf16.h>

typedef __attribute__((ext_vector_type(8))) short short8;
typedef __attribute__((ext_vector_type(4))) float f32x4;

#define D_IN   4096
#define M_TOT  8192    // B*S = 4*2048
#define N_TOT  4096
#define BM     128
#define BN     128
#define BK     64

// ---------- helpers ----------
__device__ __forceinline__ unsigned short f2bf(float f) {
  union { float f; unsigned int u; } v; v.f = f;
  unsigned int r = v.u + 0x7fffu + ((v.u >> 16) & 1u);   // round-nearest-even
  return (unsigned short)(r >> 16);
}

__device__ __forceinline__ void async16(const void* gptr, void* lptr) {
  __builtin_amdgcn_global_load_lds(
      (const __attribute__((address_space(1))) void*)gptr,
      (__attribute__((address_space(3))) void*)lptr, 16, 0, 0);
}

// ---------- kernel 1: z = bf16(x * golay) ----------
__global__ void prep_x_kernel(const float* __restrict__ x,
                              const float* __restrict__ golay,
                              unsigned short* __restrict__ z) {
  size_t i = ((size_t)blockIdx.x * 256 + threadIdx.x) * 8;
  const float4* xp = (const float4*)(x + i);
  float4 v0 = xp[0];
  float4 v1 = xp[1];
  int k = (int)(i & (D_IN - 1));          // 8 | 4096 so no wrap within chunk
  const float4* gp = (const float4*)(golay + k);
  float4 g0 = gp[0];
  float4 g1 = gp[1];
  union { unsigned short u[8]; uint4 v; } o;
  o.u[0] = f2bf(v0.x * g0.x);
  o.u[1] = f2bf(v0.y * g0.y);
  o.u[2] = f2bf(v0.z * g0.z);
  o.u[3] = f2bf(v0.w * g0.w);
  o.u[4] = f2bf(v1.x * g1.x);
  o.u[5] = f2bf(v1.y * g1.y);
  o.u[6] = f2bf(v1.z * g1.z);
  o.u[7] = f2bf(v1.w * g1.w);
  *(uint4*)(z + i) = o.v;
}

// ---------- kernel 2: Wt[o,:] = bf16( H * W[o,:] ), H = normalized natural-order Hadamard ----------
__global__ void fwht_w_kernel(const float* __restrict__ W,
                              unsigned short* __restrict__ Wt) {
  __shared__ float row[D_IN];
  const int o = blockIdx.x;
  const int tid = threadIdx.x;
  const float4* src = (const float4*)(W + (size_t)o * D_IN);
  for (int i = tid; i < D_IN / 4; i += 256)
    ((float4*)row)[i] = src[i];
  __syncthreads();
  // 12 butterfly stages (unnormalized; fold (1/sqrt2)^12 = 2^-6 into the final write)
  for (int s = 0; s < 12; ++s) {
    const int h = 1 << s;
    #pragma unroll
    for (int pp = 0; pp < 8; ++pp) {
      int p = tid + pp * 256;              // 2048 pairs
      int i = ((p >> s) << (s + 1)) | (p & (h - 1));
      int j = i + h;
      float a = row[i], b = row[j];
      row[i] = a + b;
      row[j] = a - b;
    }
    __syncthreads();
  }
  unsigned short* dst = Wt + (size_t)o * D_IN;
  for (int i = tid; i < D_IN; i += 256)
    dst[i] = f2bf(row[i] * 0.015625f);
}

// ---------- kernel 3: C = Z * Wt^T + bias  (M=8192, N=4096, K=4096, bf16 MFMA) ----------
__global__ __launch_bounds__(256) void gemm_bt_kernel(
    const unsigned short* __restrict__ Z,    // [M_TOT][D_IN] bf16 bits
    const unsigned short* __restrict__ Wt,   // [N_TOT][D_IN] bf16 bits
    const float* __restrict__ bias,          // [N_TOT]
    float* __restrict__ C) {                 // [M_TOT][N_TOT]
  __shared__ unsigned short As[BM * BK];
  __shared__ unsigned short Bs[BN * BK];

  // XCD-aware bijective swizzle (grid = 2048, 2048 % 8 == 0)
  const int nwg = gridDim.x;
  const int cpx = nwg >> 3;
  const int wg  = (blockIdx.x & 7) * cpx + (blockIdx.x >> 3);
  const int NTN = N_TOT / BN;              // 32
  const int bm0 = (wg / NTN) * BM;
  const int bn0 = (wg % NTN) * BN;

  const int tid = threadIdx.x;
  const int wv  = tid >> 6;                // wave 0..3
  const int ln  = tid & 63;
  const int lr  = ln & 15;                 // fragment row/col selector
  const int lk  = ln >> 4;                 // k-group 0..3
  const int wr  = wv >> 1;                 // wave row 0..1  (64-row panel)
  const int wc  = wv & 1;                  // wave col 0..1  (64-col panel)

  f32x4 acc[4][4] = {};

  // staging geometry: per instruction, one wave writes 8 rows x 64 cols (1 KiB LDS, linear).
  const int srow_base = wv * 8 + (ln >> 3); // + it*32
  const int sch       = ln & 7;             // 16B chunk within the 128B row

  for (int kt = 0; kt < D_IN / BK; ++kt) {
    const int kbase = kt * BK;
    #pragma unroll
    for (int it = 0; it < 4; ++it) {
      const int row = it * 32 + srow_base;
      const int gch = sch ^ (row & 7);     // pre-swizzled global source (involution)
      async16(Z  + (size_t)(bm0 + row) * D_IN + kbase + gch * 8, &As[row * BK + sch * 8]);
      async16(Wt + (size_t)(bn0 + row) * D_IN + kbase + gch * 8, &Bs[row * BK + sch * 8]);
    }
    __syncthreads();   // drains vmcnt(0): staged data visible

    #pragma unroll
    for (int ks = 0; ks < 2; ++ks) {
      short8 a[4], b[4];
      const int lc = ks * 4 + lk;          // logical 16B chunk of the fragment
      #pragma unroll
      for (int f = 0; f < 4; ++f) {
        const int ra = wr * 64 + f * 16 + lr;
        a[f] = *(const short8*)&As[ra * BK + ((lc ^ (ra & 7)) * 8)];
        const int rb = wc * 64 + f * 16 + lr;
        b[f] = *(const short8*)&Bs[rb * BK + ((lc ^ (rb & 7)) * 8)];
      }
      #pragma unroll
      for (int m = 0; m < 4; ++m)
        #pragma unroll
        for (int n = 0; n < 4; ++n)
          acc[m][n] = __builtin_amdgcn_mfma_f32_16x16x32_bf16(a[m], b[n], acc[m][n], 0, 0, 0);
    }
    __syncthreads();   // protect LDS before next-tile staging
  }

  // epilogue: C/D layout col = lane&15, row = (lane>>4)*4 + reg
  const int cm = bm0 + wr * 64 + lk * 4;
  const int cn = bn0 + wc * 64 + lr;
  #pragma unroll
  for (int n = 0; n < 4; ++n) {
    const float bv = bias[cn + n * 16];
    #pragma unroll
    for (int m = 0; m < 4; ++m) {
      #pragma unroll
      for (int r = 0; r < 4; ++r) {
        C[(size_t)(cm + m * 16 + r) * N_TOT + cn + n * 16] = acc[m][n][r] + bv;
      }
    }
  }
}

extern "C" void kernel_launch(void* const* d_in, const int* in_sizes, int n_in,
                              void* d_out, int out_size, void* d_ws, size_t ws_size,
                              hipStream_t stream) {
  const float* x     = (const float*)d_in[0];   // [4,2048,4096] fp32
  const float* golay = (const float*)d_in[1];   // [4096] fp32 (+-1)
  const float* W     = (const float*)d_in[2];   // [4096,4096] fp32
  const float* bias  = (const float*)d_in[3];   // [4096] fp32
  float* out         = (float*)d_out;           // [4,2048,4096] fp32

  unsigned short* z  = (unsigned short*)d_ws;                              // 64 MiB bf16
  unsigned short* wt = (unsigned short*)((char*)d_ws + (size_t)M_TOT * D_IN * 2); // 32 MiB bf16

  // 1) z = bf16(x * golay): 33.5M elems, 8 per thread
  prep_x_kernel<<<(M_TOT * D_IN) / (256 * 8), 256, 0, stream>>>(x, golay, z);
  // 2) Wt = bf16(rowwise FWHT of W)
  fwht_w_kernel<<<N_TOT, 256, 0, stream>>>(W, wt);
  // 3) GEMM + bias
  gemm_bt_kernel<<<(M_TOT / BM) * (N_TOT / BN), 256, 0, stream>>>(z, wt, bias, out);
}

// Round 3
// 529.417 us; speedup vs baseline: 1.2911x; 1.2911x over previous
//
#include <hip/hip_runtime.h>
#include <hip/hip_bf16.h>

typedef __attribute__((ext_vector_type(8))) short short8;
typedef __attribute__((ext_vector_type(4))) float f32x4;

#define D_IN   4096
#define M_TOT  8192    // B*S = 4*2048
#define N_TOT  4096
#define BM     256
#define BN     256
#define BK     32
#define NT     (D_IN / BK)     // 128 K-tiles
#define SLOT_SH 16384          // shorts per ring slot (A 8192 + B 8192) = 32 KiB

// ---------- helpers ----------
__device__ __forceinline__ unsigned short f2bf(float f) {
  union { float f; unsigned int u; } v; v.f = f;
  unsigned int r = v.u + 0x7fffu + ((v.u >> 16) & 1u);   // round-nearest-even
  return (unsigned short)(r >> 16);
}

__device__ __forceinline__ void async16(const void* gptr, void* lptr) {
  __builtin_amdgcn_global_load_lds(
      (const __attribute__((address_space(1))) void*)gptr,
      (__attribute__((address_space(3))) void*)lptr, 16, 0, 0);
}

// ---------- kernel 1: z = bf16(x * golay), 4 elems/thread, fully coalesced ----------
__global__ __launch_bounds__(256) void prep_x_kernel(const float* __restrict__ x,
                                                     const float* __restrict__ golay,
                                                     unsigned short* __restrict__ z) {
  size_t i = ((size_t)blockIdx.x * 256 + threadIdx.x) * 4;
  float4 v = *(const float4*)(x + i);
  float4 g = *(const float4*)(golay + (i & (D_IN - 1)));
  union { unsigned short u[4]; uint2 v; } o;
  o.u[0] = f2bf(v.x * g.x);
  o.u[1] = f2bf(v.y * g.y);
  o.u[2] = f2bf(v.z * g.z);
  o.u[3] = f2bf(v.w * g.w);
  *(uint2*)(z + i) = o.v;
}

// ---------- kernel 2: Wt[o,:] = bf16(H * W[o,:]) — 3-pass register-blocked FWHT ----------
__device__ __forceinline__ void butterfly16(float v[16]) {
  #pragma unroll
  for (int s = 0; s < 4; ++s) {
    const int h = 1 << s;
    #pragma unroll
    for (int p = 0; p < 8; ++p) {
      const int i = ((p >> s) << (s + 1)) | (p & (h - 1));
      const int j = i | h;
      float a = v[i], b = v[j];
      v[i] = a + b;
      v[j] = a - b;
    }
  }
}

__global__ __launch_bounds__(256) void fwht_w_kernel(const float* __restrict__ W,
                                                     unsigned short* __restrict__ Wt) {
  __shared__ float lds[D_IN];
  const int o = blockIdx.x;
  const int tid = threadIdx.x;
  const int tHi = tid >> 4, tLo = tid & 15;
  float v[16];

  // pass 1: load 16 consecutive (digit i0 varies), butterfly bits 0-3
  {
    const float4* src = (const float4*)(W + (size_t)o * D_IN + tid * 16);
    #pragma unroll
    for (int q = 0; q < 4; ++q) {
      float4 t = src[q];
      v[q * 4 + 0] = t.x; v[q * 4 + 1] = t.y; v[q * 4 + 2] = t.z; v[q * 4 + 3] = t.w;
    }
  }
  butterfly16(v);
  // scatter perm(i) = i0*256 + i2*16 + i1   (thread holds i2=tHi, i1=tLo, i0=j)
  #pragma unroll
  for (int j = 0; j < 16; ++j) lds[j * 256 + tHi * 16 + tLo] = v[j];
  __syncthreads();

  // pass 2: read consecutive (now i1 varies per thread), butterfly bits 4-7
  {
    const float4* src = (const float4*)(lds + tid * 16);
    #pragma unroll
    for (int q = 0; q < 4; ++q) {
      float4 t = src[q];
      v[q * 4 + 0] = t.x; v[q * 4 + 1] = t.y; v[q * 4 + 2] = t.z; v[q * 4 + 3] = t.w;
    }
  }
  butterfly16(v);
  __syncthreads();                  // all reads done before overwrite
  // thread holds i0=tHi, i2=tLo, i1=j; scatter perm2(i) = i1*256 + i0*16 + i2
  #pragma unroll
  for (int j = 0; j < 16; ++j) lds[j * 256 + tHi * 16 + tLo] = v[j];
  __syncthreads();

  // pass 3: read consecutive (now i2 varies), butterfly bits 8-11
  {
    const float4* src = (const float4*)(lds + tid * 16);
    #pragma unroll
    for (int q = 0; q < 4; ++q) {
      float4 t = src[q];
      v[q * 4 + 0] = t.x; v[q * 4 + 1] = t.y; v[q * 4 + 2] = t.z; v[q * 4 + 3] = t.w;
    }
  }
  butterfly16(v);
  // thread holds i1=tHi, i0=tLo, i2=j  →  i = j*256 + tHi*16 + tLo = j*256 + tid
  unsigned short* dst = Wt + (size_t)o * D_IN;
  #pragma unroll
  for (int j = 0; j < 16; ++j)
    dst[j * 256 + tid] = f2bf(v[j] * 0.015625f);   // (1/sqrt2)^12 = 2^-6
}

// ---------- kernel 3: C = Z * Wt^T + bias, 256x256 tile, counted-vmcnt 4-slot ring ----------
__device__ __forceinline__ void stage_tile(const unsigned short* __restrict__ Z,
                                           const unsigned short* __restrict__ Wt,
                                           unsigned short* lds, int t,
                                           int bm0, int bn0, int w, int ln, int gch) {
  unsigned short* sA = lds + (t & 3) * SLOT_SH;
  unsigned short* sB = sA + 8192;
  const int kof = t * BK + gch * 8;
  #pragma unroll
  for (int l = 0; l < 2; ++l) {
    const int row = w * 32 + l * 16 + (ln >> 2);
    const int dst = w * 1024 + l * 512 + ln * 8;   // linear: row*32 + (ln&3)*8
    async16(Z  + (size_t)(bm0 + row) * D_IN + kof, sA + dst);
    async16(Wt + (size_t)(bn0 + row) * D_IN + kof, sB + dst);
  }
}

__device__ __forceinline__ void compute_tile(const unsigned short* lds, int t,
                                             int abase, int bbase, f32x4 acc[8][4]) {
  const unsigned short* sA = lds + (t & 3) * SLOT_SH + abase;
  const unsigned short* sB = lds + (t & 3) * SLOT_SH + 8192 + bbase;
  short8 a[8], b[4];
  #pragma unroll
  for (int f = 0; f < 8; ++f) a[f] = *(const short8*)(sA + f * 512);
  #pragma unroll
  for (int n = 0; n < 4; ++n) b[n] = *(const short8*)(sB + n * 512);
  __builtin_amdgcn_s_setprio(1);
  #pragma unroll
  for (int f = 0; f < 8; ++f)
    #pragma unroll
    for (int n = 0; n < 4; ++n)
      acc[f][n] = __builtin_amdgcn_mfma_f32_16x16x32_bf16(a[f], b[n], acc[f][n], 0, 0, 0);
  __builtin_amdgcn_s_setprio(0);
}

#define TILE_SYNC(VM)                                        \
  __builtin_amdgcn_sched_barrier(0);                         \
  asm volatile("s_waitcnt lgkmcnt(0)" ::: "memory");         \
  asm volatile("s_waitcnt vmcnt(" #VM ")" ::: "memory");     \
  __builtin_amdgcn_s_barrier();

__global__ __launch_bounds__(512, 2) void gemm_bt_kernel(
    const unsigned short* __restrict__ Z,    // [M_TOT][D_IN] bf16 bits
    const unsigned short* __restrict__ Wt,   // [N_TOT][D_IN] bf16 bits
    const float* __restrict__ bias,          // [N_TOT]
    float* __restrict__ C) {                 // [M_TOT][N_TOT]
  extern __shared__ unsigned short lds[];    // 4 ring slots x (A 16K + B 16K) = 128 KiB

  // XCD-aware swizzle (grid = 512, 512 % 8 == 0)
  const int cpx = gridDim.x >> 3;
  const int wg  = ((int)blockIdx.x & 7) * cpx + ((int)blockIdx.x >> 3);
  const int NTN = N_TOT / BN;              // 16
  const int bm0 = (wg / NTN) * BM;
  const int bn0 = (wg % NTN) * BN;

  const int tid = threadIdx.x;
  const int w   = tid >> 6;                // wave 0..7
  const int ln  = tid & 63;
  const int lr  = ln & 15;
  const int ck  = ln >> 4;                 // k-chunk 0..3
  const int wr  = w >> 2;                  // wave M row 0..1 (128-row panel)
  const int wc  = w & 3;                   // wave N col 0..3 (64-col panel)

  // per-lane constant XOR swizzles (chunk-granular, involution; 2-way bank aliasing only)
  const int gch = (ln & 3) ^ ((ln >> 2) & 3) ^ (ln >> 4);       // stage source chunk
  const int swz = ck ^ (lr & 3) ^ ((lr >> 2) & 3);              // fragment read chunk
  const int abase = (wr * 128 + lr) * 32 + swz * 8;
  const int bbase = (wc * 64  + lr) * 32 + swz * 8;

  f32x4 acc[8][4] = {};

  // prologue: fill 3 ring slots, wait first tile landed (8 loads in flight)
  stage_tile(Z, Wt, lds, 0, bm0, bn0, w, ln, gch);
  stage_tile(Z, Wt, lds, 1, bm0, bn0, w, ln, gch);
  stage_tile(Z, Wt, lds, 2, bm0, bn0, w, ln, gch);
  asm volatile("s_waitcnt vmcnt(8)" ::: "memory");
  __builtin_amdgcn_s_barrier();

  // main loop: stage t+3, compute t, wait so t+1 is landed (never drain to 0)
  for (int t = 0; t < NT - 3; ++t) {
    stage_tile(Z, Wt, lds, t + 3, bm0, bn0, w, ln, gch);
    compute_tile(lds, t, abase, bbase, acc);
    TILE_SYNC(8)
  }
  compute_tile(lds, NT - 3, abase, bbase, acc);
  TILE_SYNC(4)
  compute_tile(lds, NT - 2, abase, bbase, acc);
  TILE_SYNC(0)
  compute_tile(lds, NT - 1, abase, bbase, acc);

  // epilogue: C/D layout col = lane&15, row = (lane>>4)*4 + reg
  const int cm = bm0 + wr * 128;
  const int cn = bn0 + wc * 64 + lr;
  #pragma unroll
  for (int n = 0; n < 4; ++n) {
    const float bv = bias[cn + n * 16];
    #pragma unroll
    for (int f = 0; f < 8; ++f) {
      #pragma unroll
      for (int r = 0; r < 4; ++r) {
        C[(size_t)(cm + f * 16 + ck * 4 + r) * N_TOT + cn + n * 16] = acc[f][n][r] + bv;
      }
    }
  }
}

extern "C" void kernel_launch(void* const* d_in, const int* in_sizes, int n_in,
                              void* d_out, int out_size, void* d_ws, size_t ws_size,
                              hipStream_t stream) {
  const float* x     = (const float*)d_in[0];   // [4,2048,4096] fp32
  const float* golay = (const float*)d_in[1];   // [4096] fp32 (+-1)
  const float* W     = (const float*)d_in[2];   // [4096,4096] fp32
  const float* bias  = (const float*)d_in[3];   // [4096] fp32
  float* out         = (float*)d_out;           // [4,2048,4096] fp32

  unsigned short* z  = (unsigned short*)d_ws;                                    // 64 MiB bf16
  unsigned short* wt = (unsigned short*)((char*)d_ws + (size_t)M_TOT * D_IN * 2); // 32 MiB bf16

  prep_x_kernel<<<(M_TOT * D_IN) / (256 * 4), 256, 0, stream>>>(x, golay, z);
  fwht_w_kernel<<<N_TOT, 256, 0, stream>>>(W, wt);
  gemm_bt_kernel<<<(M_TOT / BM) * (N_TOT / BN), 512, 4 * SLOT_SH * 2, stream>>>(z, wt, bias, out);
}